// Round 1
// baseline (1091.920 us; speedup 1.0000x reference)
//
#include <hip/hip_runtime.h>
#include <cstdint>
#include <type_traits>

typedef unsigned int u32;
typedef unsigned short u16;
typedef short v8s __attribute__((ext_vector_type(8)));
typedef float v4f __attribute__((ext_vector_type(4)));

#define B_ 8
#define C_ 192
#define HW_ 16384
#define C4_ 768

__device__ __forceinline__ float b2f(u16 u) {
  union { u32 i; float f; } v; v.i = ((u32)u) << 16; return v.f;
}
__device__ __forceinline__ u16 f2b(float f) {
  union { float f; u32 i; } v; v.f = f;
  u32 r = v.i + 0x7fffu + ((v.i >> 16) & 1u);
  return (u16)(r >> 16);
}
__device__ __forceinline__ void b2f2(u32 u, float& a, float& b) {
  union { u32 i; float f; } x, y;
  x.i = u << 16; y.i = u & 0xffff0000u;
  a = x.f; b = y.f;
}
__device__ __forceinline__ float sigm(float x) { return 1.f / (1.f + expf(-x)); }
__device__ __forceinline__ u32 pk2(u16 a, u16 b) { return (u32)a | ((u32)b << 16); }

// ---------------- weights fp32 -> bf16 ----------------
__global__ __launch_bounds__(256) void k_f2b(const float* __restrict__ in, u16* __restrict__ out, int n) {
  int i = blockIdx.x * 256 + threadIdx.x;
  if (i < n) out[i] = f2b(in[i]);
}

// ---------------- channel avg/max pool over HW ----------------
__global__ __launch_bounds__(256) void k_channel_pool(const float* __restrict__ x,
                                                      float* __restrict__ avg, float* __restrict__ mx_) {
  int c = blockIdx.x, b = blockIdx.y, t = threadIdx.x;
  const float4* p = (const float4*)(x + (((size_t)b * C_ + c) << 14));
  float s = 0.f, m = -INFINITY;
  for (int i = t; i < 4096; i += 256) {
    float4 v = p[i];
    s += v.x + v.y + v.z + v.w;
    m = fmaxf(m, fmaxf(fmaxf(v.x, v.y), fmaxf(v.z, v.w)));
  }
  __shared__ float ss[256], sm[256];
  ss[t] = s; sm[t] = m; __syncthreads();
  for (int o = 128; o > 0; o >>= 1) {
    if (t < o) { ss[t] += ss[t + o]; sm[t] = fmaxf(sm[t], sm[t + o]); }
    __syncthreads();
  }
  if (t == 0) { avg[b * C_ + c] = ss[0] * (1.f / 16384.f); mx_[b * C_ + c] = sm[0]; }
}

// ---------------- SE channel gate ----------------
__global__ __launch_bounds__(256) void k_channel_gate(const float* __restrict__ avg, const float* __restrict__ mx_,
                                                      const float* __restrict__ wfc1, const float* __restrict__ wfc2,
                                                      float* __restrict__ cgate) {
  int b = blockIdx.x, t = threadIdx.x;
  __shared__ float pool[384], sq[48];
  if (t < 192) { pool[t] = avg[b * C_ + t]; pool[192 + t] = mx_[b * C_ + t]; }
  __syncthreads();
  if (t < 48) {
    float s = 0.f;
    for (int k = 0; k < 384; ++k) s += wfc1[t * 384 + k] * pool[k];
    sq[t] = fmaxf(s, 0.f);
  }
  __syncthreads();
  if (t < 192) {
    float s = 0.f;
    for (int j = 0; j < 48; ++j) s += wfc2[t * 48 + j] * sq[j];
    cgate[b * C_ + t] = sigm(s);
  }
}

// ---------------- spatial mean/max over channels ----------------
__global__ __launch_bounds__(256) void k_spatial_pool(const float* __restrict__ x, float* __restrict__ sp) {
  int b = blockIdx.y;
  int p = blockIdx.x * 256 + threadIdx.x;
  const float* xb = x + (((size_t)b * C_) << 14);
  float s = 0.f, m = -INFINITY;
#pragma unroll 4
  for (int c = 0; c < C_; ++c) {
    float v = xb[((size_t)c << 14) + p];
    s += v; m = fmaxf(m, v);
  }
  sp[(size_t)b * 32768 + p] = s * (1.f / 192.f);
  sp[(size_t)b * 32768 + 16384 + p] = m;
}

// ---------------- 7x7 conv (2->1 ch) + sigmoid ----------------
__global__ __launch_bounds__(256) void k_spatial_conv(const float* __restrict__ sp, const float* __restrict__ wsp,
                                                      float* __restrict__ sg) {
  int b = blockIdx.y;
  int p = blockIdx.x * 256 + threadIdx.x;
  int y = p >> 7, xx = p & 127;
  const float* s0 = sp + (size_t)b * 32768;
  float acc = 0.f;
  for (int ic = 0; ic < 2; ++ic)
    for (int ky = 0; ky < 7; ++ky) {
      int yy = y + ky - 3;
      if ((unsigned)yy >= 128u) continue;
      for (int kx = 0; kx < 7; ++kx) {
        int xp = xx + kx - 3;
        if ((unsigned)xp >= 128u) continue;
        acc += wsp[ic * 49 + ky * 7 + kx] * s0[ic * 16384 + yy * 128 + xp];
      }
    }
  sg[(size_t)b * 16384 + p] = sigm(acc);
}

// ---------------- gated x, transposed to [hw][c] bf16 ----------------
__global__ __launch_bounds__(256) void k_gxT(const float* __restrict__ x, const float* __restrict__ cg,
                                             const float* __restrict__ sg, u16* __restrict__ gxT, int b0) {
  int zb = blockIdx.y, b = b0 + zb, t = threadIdx.x;
  int hw0 = blockIdx.x * 64;
  __shared__ alignas(16) u16 Ls[64][196];
  int hwi = t & 63, grp = t >> 6;
  float sgv = sg[(size_t)b * 16384 + hw0 + hwi];
  for (int it = 0; it < 48; ++it) {
    int c = it * 4 + grp;
    float v = x[(((size_t)b * C_ + c) << 14) + hw0 + hwi] * cg[b * C_ + c] * sgv;
    Ls[hwi][c] = f2b(v);
  }
  __syncthreads();
  u32* out = (u32*)gxT;
  for (int r = 0; r < 24; ++r) {
    int ci = r * 256 + t;          // 64 rows * 96 uints
    int row = ci / 96, col = ci - row * 96;
    u32 v = *(const u32*)&Ls[row][col * 2];
    out[((size_t)zb * HW_ + hw0 + row) * 96 + col] = v;
  }
}

// ---------------- bf16 MFMA GEMM: C[b][M][16384] = A[M][192] * BT[b][16384][192]^T ----------------
template <int M, typename OutT>
__global__ __launch_bounds__(256) void gemm_bt(const u16* __restrict__ A, const u16* __restrict__ BT,
                                               OutT* __restrict__ C) {
  const int K = 192;
  int b = blockIdx.z;
  int n0 = blockIdx.x * 128, m0 = blockIdx.y * 128;
  const u16* Bb = BT + (size_t)b * HW_ * K;
  __shared__ alignas(16) u16 As[128][40];
  __shared__ alignas(16) u16 Bs[128][40];
  int t = threadIdx.x;
  int wave = t >> 6, lane = t & 63, l16 = lane & 15, quad = lane >> 4;
  int wr = wave >> 1, wc = wave & 1;
  v4f acc[4][4] = {};
  for (int kc = 0; kc < K; kc += 32) {
#pragma unroll
    for (int r = 0; r < 2; ++r) {
      int ci = r * 256 + t;          // 512 chunks of 8 bf16
      int row = ci >> 2, ks = (ci & 3) * 8;
      uint4 av; av.x = av.y = av.z = av.w = 0u;
      if (m0 + row < M) av = *(const uint4*)(A + (size_t)(m0 + row) * K + kc + ks);
      *(uint4*)&As[row][ks] = av;
      uint4 bv = *(const uint4*)(Bb + (size_t)(n0 + row) * K + kc + ks);
      *(uint4*)&Bs[row][ks] = bv;
    }
    __syncthreads();
    v8s af[4], bf[4];
#pragma unroll
    for (int mt = 0; mt < 4; ++mt) af[mt] = *(const v8s*)&As[wr * 64 + mt * 16 + l16][quad * 8];
#pragma unroll
    for (int nt = 0; nt < 4; ++nt) bf[nt] = *(const v8s*)&Bs[wc * 64 + nt * 16 + l16][quad * 8];
#pragma unroll
    for (int mt = 0; mt < 4; ++mt)
#pragma unroll
      for (int nt = 0; nt < 4; ++nt)
        acc[mt][nt] = __builtin_amdgcn_mfma_f32_16x16x32_bf16(af[mt], bf[nt], acc[mt][nt], 0, 0, 0);
    __syncthreads();
  }
#pragma unroll
  for (int mt = 0; mt < 4; ++mt) {
    int m = m0 + wr * 64 + mt * 16 + quad * 4;
#pragma unroll
    for (int nt = 0; nt < 4; ++nt) {
      int n = n0 + wc * 64 + nt * 16 + l16;
#pragma unroll
      for (int r = 0; r < 4; ++r) {
        if (m + r < M) {
          float v = acc[mt][nt][r];
          size_t off = ((size_t)b * M + (m + r)) * (size_t)HW_ + n;
          if constexpr (std::is_same<OutT, u16>::value) C[off] = f2b(v);
          else C[off] = v;
        }
      }
    }
  }
}

// ---------------- depthwise 3x3 (bf16 in/out, fp32 acc) ----------------
__global__ __launch_bounds__(256) void k_dw(const u16* __restrict__ in, const float* __restrict__ wdw,
                                            u16* __restrict__ out) {
  int oc = blockIdx.y;
  size_t base = ((size_t)(blockIdx.z * C4_ + oc)) << 14;
  int p = blockIdx.x * 256 + threadIdx.x;
  int y = p >> 7, xx = p & 127;
  const float* wd = wdw + oc * 9;
  float acc = 0.f;
#pragma unroll
  for (int ky = 0; ky < 3; ++ky) {
    int yy = y + ky - 1;
    if ((unsigned)yy >= 128u) continue;
#pragma unroll
    for (int kx = 0; kx < 3; ++kx) {
      int xp = xx + kx - 1;
      if ((unsigned)xp >= 128u) continue;
      acc += wd[ky * 3 + kx] * b2f(in[base + yy * 128 + xp]);
    }
  }
  out[base + p] = f2b(acc);
}

// ---------------- inverse L2 norms of q and k over hw ----------------
__global__ __launch_bounds__(256) void k_rnorm(const u16* __restrict__ qkv, float* __restrict__ rqn,
                                               float* __restrict__ rkn, int b0) {
  int j = blockIdx.x, zb = blockIdx.y, b = b0 + zb, t = threadIdx.x;
  int ch = (j < 192) ? j : (384 + j - 192);
  const uint4* p = (const uint4*)(qkv + (((size_t)zb * C4_ + ch) << 14));
  float s = 0.f;
  for (int i = t; i < 2048; i += 256) {
    uint4 v = p[i];
    float a, c;
    b2f2(v.x, a, c); s += a * a + c * c;
    b2f2(v.y, a, c); s += a * a + c * c;
    b2f2(v.z, a, c); s += a * a + c * c;
    b2f2(v.w, a, c); s += a * a + c * c;
  }
  __shared__ float ss[256];
  ss[t] = s; __syncthreads();
  for (int o = 128; o > 0; o >>= 1) {
    if (t < o) ss[t] += ss[t + o];
    __syncthreads();
  }
  if (t == 0) {
    float r = 1.f / fmaxf(sqrtf(ss[0]), 1e-12f);
    if (j < 192) rqn[b * C_ + j] = r; else rkn[b * C_ + (j - 192)] = r;
  }
}

// ---------------- QK^T raw partial dots via MFMA ----------------
__global__ __launch_bounds__(256) void k_qk(const u16* __restrict__ qkv, float* __restrict__ Spart, int b0) {
  int split = blockIdx.x;
  int zb = blockIdx.y >> 2, h = blockIdx.y & 3;
  int bh = (b0 + zb) * 4 + h;
  int t = threadIdx.x, w = t >> 6, lane = t & 63, l16 = lane & 15, quad = lane >> 4;
  __shared__ alignas(16) u16 Qs[48][136];
  __shared__ alignas(16) u16 Ks[48][136];
  const u16* qb = qkv + (((size_t)zb * C4_ + h * 48) << 14);
  const u16* kb = qkv + (((size_t)zb * C4_ + 384 + h * 48) << 14);
  v4f acc[3][3] = {};
  for (int chunk = 0; chunk < 8; ++chunk) {
    int nb = split * 1024 + chunk * 128;
#pragma unroll
    for (int r = 0; r < 3; ++r) {
      int ci = r * 256 + t;         // 768 chunks of 8
      int row = ci >> 4, cs = (ci & 15) * 8;
      *(uint4*)&Qs[row][cs] = *(const uint4*)(qb + ((size_t)row << 14) + nb + cs);
      *(uint4*)&Ks[row][cs] = *(const uint4*)(kb + ((size_t)row << 14) + nb + cs);
    }
    __syncthreads();
    v8s qf[3], kf[3];
#pragma unroll
    for (int mt = 0; mt < 3; ++mt) qf[mt] = *(const v8s*)&Qs[mt * 16 + l16][w * 32 + quad * 8];
#pragma unroll
    for (int nt = 0; nt < 3; ++nt) kf[nt] = *(const v8s*)&Ks[nt * 16 + l16][w * 32 + quad * 8];
#pragma unroll
    for (int mt = 0; mt < 3; ++mt)
#pragma unroll
      for (int nt = 0; nt < 3; ++nt)
        acc[mt][nt] = __builtin_amdgcn_mfma_f32_16x16x32_bf16(qf[mt], kf[nt], acc[mt][nt], 0, 0, 0);
    __syncthreads();
  }
  float* out = Spart + ((size_t)(split * 4 + w) * 32 + bh) * 2304;
#pragma unroll
  for (int mt = 0; mt < 3; ++mt)
#pragma unroll
    for (int nt = 0; nt < 3; ++nt)
#pragma unroll
      for (int r = 0; r < 4; ++r)
        out[(mt * 16 + quad * 4 + r) * 48 + nt * 16 + l16] = acc[mt][nt][r];
}

// ---------------- fold norms+temperature, softmax rows ----------------
__global__ __launch_bounds__(256) void k_softmax(const float* __restrict__ Spart, const float* __restrict__ rqn,
                                                 const float* __restrict__ rkn, const float* __restrict__ temp,
                                                 float* __restrict__ attn, int b0) {
  int bh = b0 * 4 + blockIdx.x;
  int b = bh >> 2, h = bh & 3, t = threadIdx.x;
  __shared__ float Sm[2304];
  float tv = temp[h];
  for (int r = 0; r < 9; ++r) {
    int e = r * 256 + t;
    float s = 0.f;
    for (int p = 0; p < 64; ++p) s += Spart[((size_t)p * 32 + bh) * 2304 + e];
    int c = e / 48, d = e - c * 48;
    Sm[e] = s * rqn[b * C_ + h * 48 + c] * rkn[b * C_ + h * 48 + d] * tv;
  }
  __syncthreads();
  if (t < 48) {
    float m = -INFINITY;
#pragma unroll
    for (int d = 0; d < 48; ++d) m = fmaxf(m, Sm[t * 48 + d]);
    float ex[48];
    float sum = 0.f;
#pragma unroll
    for (int d = 0; d < 48; ++d) { ex[d] = expf(Sm[t * 48 + d] - m); sum += ex[d]; }
    float inv = 1.f / sum;
#pragma unroll
    for (int d = 0; d < 48; ++d) attn[(size_t)bh * 2304 + t * 48 + d] = ex[d] * inv;
  }
}

// ---------------- out = (attn @ v) * sigmoid(gate), stored as ogT[hw][c] bf16 ----------------
__global__ __launch_bounds__(256) void k_av(const u16* __restrict__ qkv, const float* __restrict__ attn,
                                            u16* __restrict__ ogT, int b0) {
  int zb = blockIdx.y >> 2, h = blockIdx.y & 3;
  int bh = (b0 + zb) * 4 + h;
  int t = threadIdx.x;
  int n0 = blockIdx.x * 512;
  __shared__ alignas(16) u16 Vs[48][520];
  __shared__ alignas(16) float SlT[48][48];   // [d][c]
  for (int r = 0; r < 9; ++r) {
    int e = r * 256 + t;
    int c = e / 48, d = e - c * 48;
    SlT[d][c] = attn[(size_t)bh * 2304 + e];
  }
  const u16* vb = qkv + (((size_t)zb * C4_ + 576 + h * 48) << 14);
  for (int r = 0; r < 12; ++r) {
    int ci = r * 256 + t;           // 48 rows * 64 chunks
    int row = ci >> 6, cs = (ci & 63) * 8;
    *(uint4*)&Vs[row][cs] = *(const uint4*)(vb + ((size_t)row << 14) + n0 + cs);
  }
  __syncthreads();
  int grp = t >> 6, nl = t & 63;
  int n = n0 + nl * 8;
  float acc[12][8] = {};
  for (int d = 0; d < 48; ++d) {
    uint4 vv = *(const uint4*)&Vs[d][nl * 8];
    float v[8];
    b2f2(vv.x, v[0], v[1]); b2f2(vv.y, v[2], v[3]);
    b2f2(vv.z, v[4], v[5]); b2f2(vv.w, v[6], v[7]);
    const float4* sr = (const float4*)&SlT[d][grp * 12];
    float4 sa = sr[0], sb = sr[1], sc = sr[2];
    float sv[12] = {sa.x, sa.y, sa.z, sa.w, sb.x, sb.y, sb.z, sb.w, sc.x, sc.y, sc.z, sc.w};
#pragma unroll
    for (int cc = 0; cc < 12; ++cc)
#pragma unroll
      for (int j = 0; j < 8; ++j) acc[cc][j] += sv[cc] * v[j];
  }
  const u16* gb = qkv + (((size_t)zb * C4_ + 192 + h * 48) << 14);
#pragma unroll
  for (int cc = 0; cc < 12; ++cc) {
    int c = grp * 12 + cc;
    uint4 g4 = *(const uint4*)(gb + ((size_t)c << 14) + n);
    float g[8];
    b2f2(g4.x, g[0], g[1]); b2f2(g4.y, g[2], g[3]);
    b2f2(g4.z, g[4], g[5]); b2f2(g4.w, g[6], g[7]);
#pragma unroll
    for (int j = 0; j < 8; ++j) acc[cc][j] *= sigm(g[j]);
  }
#pragma unroll
  for (int j = 0; j < 8; ++j) {
    u16 vals[12];
#pragma unroll
    for (int cc = 0; cc < 12; ++cc) vals[cc] = f2b(acc[cc][j]);
    u16* dst = ogT + ((size_t)zb * HW_ + n + j) * 192 + h * 48 + grp * 12;
    uint2* d2 = (uint2*)dst;        // 8-byte aligned
    uint2 w0, w1, w2;
    w0.x = pk2(vals[0], vals[1]);  w0.y = pk2(vals[2], vals[3]);
    w1.x = pk2(vals[4], vals[5]);  w1.y = pk2(vals[6], vals[7]);
    w2.x = pk2(vals[8], vals[9]);  w2.y = pk2(vals[10], vals[11]);
    d2[0] = w0; d2[1] = w1; d2[2] = w2;
  }
}

// ---------------- host ----------------
extern "C" void kernel_launch(void* const* d_in, const int* in_sizes, int n_in,
                              void* d_out, int out_size, void* d_ws, size_t ws_size,
                              hipStream_t stream) {
  const float* x     = (const float*)d_in[0];
  const float* wfc1  = (const float*)d_in[1];
  const float* wfc2  = (const float*)d_in[2];
  const float* wsp   = (const float*)d_in[3];
  const float* wqkv  = (const float*)d_in[4];
  const float* wdw   = (const float*)d_in[5];
  const float* wproj = (const float*)d_in[6];
  const float* temp  = (const float*)d_in[7];
  float* out = (float*)d_out;
  char* W = (char*)d_ws;

  constexpr size_t OFF_AVG   = 0;
  constexpr size_t OFF_MAX   = 8192;
  constexpr size_t OFF_CG    = 16384;
  constexpr size_t OFF_RQN   = 24576;
  constexpr size_t OFF_RKN   = 32768;
  constexpr size_t OFF_WQB   = 40960;
  constexpr size_t OFF_WPB   = OFF_WQB + 294912;
  constexpr size_t OFF_SP    = OFF_WPB + 73728;
  constexpr size_t OFF_SG    = OFF_SP + 1048576;
  constexpr size_t OFF_ATT   = OFF_SG + 524288;
  constexpr size_t OFF_SPART = OFF_ATT + 294912;
  constexpr size_t OFF_BIG   = OFF_SPART + 18874368;
  const size_t GXT_B = (size_t)HW_ * 192 * 2;        // 6291456
  const size_t QKV_B = (size_t)C4_ * HW_ * 2;        // 25165824

  float* avg   = (float*)(W + OFF_AVG);
  float* mx    = (float*)(W + OFF_MAX);
  float* cg    = (float*)(W + OFF_CG);
  float* rqn   = (float*)(W + OFF_RQN);
  float* rkn   = (float*)(W + OFF_RKN);
  u16*   wqb   = (u16*)(W + OFF_WQB);
  u16*   wpb   = (u16*)(W + OFF_WPB);
  float* sp    = (float*)(W + OFF_SP);
  float* sg    = (float*)(W + OFF_SG);
  float* attn  = (float*)(W + OFF_ATT);
  float* Spart = (float*)(W + OFF_SPART);

  int NB = 8;
  while (NB > 1 && (OFF_BIG + (size_t)NB * (GXT_B + 2 * QKV_B)) > ws_size) NB >>= 1;

  u16* gxT  = (u16*)(W + OFF_BIG);
  u16* qkvr = (u16*)(W + OFF_BIG + (size_t)NB * GXT_B);
  u16* qkvd = (u16*)(W + OFF_BIG + (size_t)NB * (GXT_B + QKV_B));
  u16* ogT  = qkvr;   // qkv_raw dead once depthwise is done for the whole group

  k_f2b<<<(147456 + 255) / 256, 256, 0, stream>>>(wqkv, wqb, 147456);
  k_f2b<<<(36864 + 255) / 256, 256, 0, stream>>>(wproj, wpb, 36864);
  k_channel_pool<<<dim3(C_, B_), 256, 0, stream>>>(x, avg, mx);
  k_channel_gate<<<B_, 256, 0, stream>>>(avg, mx, wfc1, wfc2, cg);
  k_spatial_pool<<<dim3(64, B_), 256, 0, stream>>>(x, sp);
  k_spatial_conv<<<dim3(64, B_), 256, 0, stream>>>(sp, wsp, sg);

  for (int b0 = 0; b0 < B_; b0 += NB) {
    k_gxT<<<dim3(256, NB), 256, 0, stream>>>(x, cg, sg, gxT, b0);
    gemm_bt<768, u16><<<dim3(128, 6, NB), 256, 0, stream>>>(wqb, gxT, qkvr);
    k_dw<<<dim3(64, C4_, NB), 256, 0, stream>>>(qkvr, wdw, qkvd);
    k_rnorm<<<dim3(384, NB), 256, 0, stream>>>(qkvd, rqn, rkn, b0);
    k_qk<<<dim3(16, NB * 4), 256, 0, stream>>>(qkvd, Spart, b0);
    k_softmax<<<NB * 4, 256, 0, stream>>>(Spart, rqn, rkn, temp, attn, b0);
    k_av<<<dim3(32, NB * 4), 256, 0, stream>>>(qkvd, attn, ogT, b0);
    gemm_bt<192, float><<<dim3(128, 2, NB), 256, 0, stream>>>(wpb, ogT, out + (size_t)b0 * C_ * HW_);
  }
}

// Round 2
// 678.520 us; speedup vs baseline: 1.6093x; 1.6093x over previous
//
#include <hip/hip_runtime.h>
#include <cstdint>
#include <type_traits>

typedef unsigned int u32;
typedef unsigned short u16;
typedef short v8s __attribute__((ext_vector_type(8)));
typedef float v4f __attribute__((ext_vector_type(4)));

#define B_ 8
#define C_ 192
#define HW_ 16384
#define C4_ 768

__device__ __forceinline__ float b2f(u16 u) {
  union { u32 i; float f; } v; v.i = ((u32)u) << 16; return v.f;
}
__device__ __forceinline__ u16 f2b(float f) {
  union { float f; u32 i; } v; v.f = f;
  u32 r = v.i + 0x7fffu + ((v.i >> 16) & 1u);
  return (u16)(r >> 16);
}
__device__ __forceinline__ void b2f2(u32 u, float& a, float& b) {
  union { u32 i; float f; } x, y;
  x.i = u << 16; y.i = u & 0xffff0000u;
  a = x.f; b = y.f;
}
__device__ __forceinline__ float lo16f(u32 u) {
  union { u32 i; float f; } x; x.i = u << 16; return x.f;
}
__device__ __forceinline__ float hi16f(u32 u) {
  union { u32 i; float f; } x; x.i = u & 0xffff0000u; return x.f;
}
__device__ __forceinline__ float sigm(float x) { return 1.f / (1.f + expf(-x)); }
__device__ __forceinline__ u32 pk2(u16 a, u16 b) { return (u32)a | ((u32)b << 16); }

// ---------------- weights fp32 -> bf16 ----------------
__global__ __launch_bounds__(256) void k_f2b(const float* __restrict__ in, u16* __restrict__ out, int n) {
  int i = blockIdx.x * 256 + threadIdx.x;
  if (i < n) out[i] = f2b(in[i]);
}

// ---------------- channel avg/max pool over HW ----------------
__global__ __launch_bounds__(256) void k_channel_pool(const float* __restrict__ x,
                                                      float* __restrict__ avg, float* __restrict__ mx_) {
  int c = blockIdx.x, b = blockIdx.y, t = threadIdx.x;
  const float4* p = (const float4*)(x + (((size_t)b * C_ + c) << 14));
  float s = 0.f, m = -INFINITY;
  for (int i = t; i < 4096; i += 256) {
    float4 v = p[i];
    s += v.x + v.y + v.z + v.w;
    m = fmaxf(m, fmaxf(fmaxf(v.x, v.y), fmaxf(v.z, v.w)));
  }
  __shared__ float ss[256], sm[256];
  ss[t] = s; sm[t] = m; __syncthreads();
  for (int o = 128; o > 0; o >>= 1) {
    if (t < o) { ss[t] += ss[t + o]; sm[t] = fmaxf(sm[t], sm[t + o]); }
    __syncthreads();
  }
  if (t == 0) { avg[b * C_ + c] = ss[0] * (1.f / 16384.f); mx_[b * C_ + c] = sm[0]; }
}

// ---------------- SE channel gate ----------------
__global__ __launch_bounds__(256) void k_channel_gate(const float* __restrict__ avg, const float* __restrict__ mx_,
                                                      const float* __restrict__ wfc1, const float* __restrict__ wfc2,
                                                      float* __restrict__ cgate) {
  int b = blockIdx.x, t = threadIdx.x;
  __shared__ float pool[384], sq[48];
  if (t < 192) { pool[t] = avg[b * C_ + t]; pool[192 + t] = mx_[b * C_ + t]; }
  __syncthreads();
  if (t < 48) {
    float s = 0.f;
    for (int k = 0; k < 384; ++k) s += wfc1[t * 384 + k] * pool[k];
    sq[t] = fmaxf(s, 0.f);
  }
  __syncthreads();
  if (t < 192) {
    float s = 0.f;
    for (int j = 0; j < 48; ++j) s += wfc2[t * 48 + j] * sq[j];
    cgate[b * C_ + t] = sigm(s);
  }
}

// ---------------- spatial mean/max over channels ----------------
__global__ __launch_bounds__(256) void k_spatial_pool(const float* __restrict__ x, float* __restrict__ sp) {
  int b = blockIdx.y;
  int p = blockIdx.x * 256 + threadIdx.x;
  const float* xb = x + (((size_t)b * C_) << 14);
  float s = 0.f, m = -INFINITY;
#pragma unroll 4
  for (int c = 0; c < C_; ++c) {
    float v = xb[((size_t)c << 14) + p];
    s += v; m = fmaxf(m, v);
  }
  sp[(size_t)b * 32768 + p] = s * (1.f / 192.f);
  sp[(size_t)b * 32768 + 16384 + p] = m;
}

// ---------------- 7x7 conv (2->1 ch) + sigmoid ----------------
__global__ __launch_bounds__(256) void k_spatial_conv(const float* __restrict__ sp, const float* __restrict__ wsp,
                                                      float* __restrict__ sg) {
  int b = blockIdx.y;
  int p = blockIdx.x * 256 + threadIdx.x;
  int y = p >> 7, xx = p & 127;
  const float* s0 = sp + (size_t)b * 32768;
  float acc = 0.f;
  for (int ic = 0; ic < 2; ++ic)
    for (int ky = 0; ky < 7; ++ky) {
      int yy = y + ky - 3;
      if ((unsigned)yy >= 128u) continue;
      for (int kx = 0; kx < 7; ++kx) {
        int xp = xx + kx - 3;
        if ((unsigned)xp >= 128u) continue;
        acc += wsp[ic * 49 + ky * 7 + kx] * s0[ic * 16384 + yy * 128 + xp];
      }
    }
  sg[(size_t)b * 16384 + p] = sigm(acc);
}

// ---------------- gated x, transposed to [hw][c] bf16 ----------------
__global__ __launch_bounds__(256) void k_gxT(const float* __restrict__ x, const float* __restrict__ cg,
                                             const float* __restrict__ sg, u16* __restrict__ gxT, int b0) {
  int zb = blockIdx.y, b = b0 + zb, t = threadIdx.x;
  int hw0 = blockIdx.x * 64;
  __shared__ alignas(16) u16 Ls[64][196];
  int hwi = t & 63, grp = t >> 6;
  float sgv = sg[(size_t)b * 16384 + hw0 + hwi];
  for (int it = 0; it < 48; ++it) {
    int c = it * 4 + grp;
    float v = x[(((size_t)b * C_ + c) << 14) + hw0 + hwi] * cg[b * C_ + c] * sgv;
    Ls[hwi][c] = f2b(v);
  }
  __syncthreads();
  u32* out = (u32*)gxT;
  for (int r = 0; r < 24; ++r) {
    int ci = r * 256 + t;          // 64 rows * 96 uints
    int row = ci / 96, col = ci - row * 96;
    u32 v = *(const u32*)&Ls[row][col * 2];
    out[((size_t)zb * HW_ + hw0 + row) * 96 + col] = v;
  }
}

// ---------------- bf16 MFMA GEMM: C[b][M][16384] = A[M][192] * BT[b][16384][192]^T ----------------
template <int M, typename OutT>
__global__ __launch_bounds__(256) void gemm_bt(const u16* __restrict__ A, const u16* __restrict__ BT,
                                               OutT* __restrict__ C) {
  const int K = 192;
  int b = blockIdx.z;
  int n0 = blockIdx.x * 128, m0 = blockIdx.y * 128;
  const u16* Bb = BT + (size_t)b * HW_ * K;
  __shared__ alignas(16) u16 As[128][40];
  __shared__ alignas(16) u16 Bs[128][40];
  int t = threadIdx.x;
  int wave = t >> 6, lane = t & 63, l16 = lane & 15, quad = lane >> 4;
  int wr = wave >> 1, wc = wave & 1;
  v4f acc[4][4] = {};
  for (int kc = 0; kc < K; kc += 32) {
#pragma unroll
    for (int r = 0; r < 2; ++r) {
      int ci = r * 256 + t;          // 512 chunks of 8 bf16
      int row = ci >> 2, ks = (ci & 3) * 8;
      uint4 av; av.x = av.y = av.z = av.w = 0u;
      if (m0 + row < M) av = *(const uint4*)(A + (size_t)(m0 + row) * K + kc + ks);
      *(uint4*)&As[row][ks] = av;
      uint4 bv = *(const uint4*)(Bb + (size_t)(n0 + row) * K + kc + ks);
      *(uint4*)&Bs[row][ks] = bv;
    }
    __syncthreads();
    v8s af[4], bf[4];
#pragma unroll
    for (int mt = 0; mt < 4; ++mt) af[mt] = *(const v8s*)&As[wr * 64 + mt * 16 + l16][quad * 8];
#pragma unroll
    for (int nt = 0; nt < 4; ++nt) bf[nt] = *(const v8s*)&Bs[wc * 64 + nt * 16 + l16][quad * 8];
#pragma unroll
    for (int mt = 0; mt < 4; ++mt)
#pragma unroll
      for (int nt = 0; nt < 4; ++nt)
        acc[mt][nt] = __builtin_amdgcn_mfma_f32_16x16x32_bf16(af[mt], bf[nt], acc[mt][nt], 0, 0, 0);
    __syncthreads();
  }
#pragma unroll
  for (int mt = 0; mt < 4; ++mt) {
    int m = m0 + wr * 64 + mt * 16 + quad * 4;
#pragma unroll
    for (int nt = 0; nt < 4; ++nt) {
      int n = n0 + wc * 64 + nt * 16 + l16;
#pragma unroll
      for (int r = 0; r < 4; ++r) {
        if (m + r < M) {
          float v = acc[mt][nt][r];
          size_t off = ((size_t)b * M + (m + r)) * (size_t)HW_ + n;
          if constexpr (std::is_same<OutT, u16>::value) C[off] = f2b(v);
          else C[off] = v;
        }
      }
    }
  }
}

// ---------------- depthwise 3x3 (bf16 in/out, fp32 acc) ----------------
// Each thread: 8 contiguous x-pixels; 3 uint4 row loads; halo via shfl.
__global__ __launch_bounds__(256) void k_dw(const u16* __restrict__ in, const float* __restrict__ wdw,
                                            u16* __restrict__ out) {
  int oc = blockIdx.y;
  size_t base = ((size_t)(blockIdx.z * C4_ + oc)) << 14;
  int t = threadIdx.x;
  int p0 = blockIdx.x * 2048 + t * 8;    // 8 px per thread, 16 rows per block
  int y = p0 >> 7;
  int xseg = t & 15;                     // segment index within image row (8 px each)
  const float* wd = wdw + oc * 9;
  float w0 = wd[0], w1 = wd[1], w2 = wd[2];
  float w3 = wd[3], w4 = wd[4], w5 = wd[5];
  float w6 = wd[6], w7 = wd[7], w8 = wd[8];

  float r[3][10];
#pragma unroll
  for (int ky = 0; ky < 3; ++ky) {
    int yy = y + ky - 1;
    uint4 v; v.x = v.y = v.z = v.w = 0u;
    if ((unsigned)yy < 128u) v = *(const uint4*)(in + base + ((size_t)yy << 7) + (p0 & 127));
    b2f2(v.x, r[ky][1], r[ky][2]);
    b2f2(v.y, r[ky][3], r[ky][4]);
    b2f2(v.z, r[ky][5], r[ky][6]);
    b2f2(v.w, r[ky][7], r[ky][8]);
    u32 pw = (u32)__shfl_up((int)v.w, 1);    // lane-1's last pair
    u32 nx = (u32)__shfl_down((int)v.x, 1);  // lane+1's first pair
    r[ky][0] = (xseg == 0) ? 0.f : hi16f(pw);
    r[ky][9] = (xseg == 15) ? 0.f : lo16f(nx);
  }

  float acc[8];
#pragma unroll
  for (int j = 0; j < 8; ++j) {
    acc[j] = w0 * r[0][j] + w1 * r[0][j + 1] + w2 * r[0][j + 2]
           + w3 * r[1][j] + w4 * r[1][j + 1] + w5 * r[1][j + 2]
           + w6 * r[2][j] + w7 * r[2][j + 1] + w8 * r[2][j + 2];
  }
  uint4 o;
  o.x = pk2(f2b(acc[0]), f2b(acc[1]));
  o.y = pk2(f2b(acc[2]), f2b(acc[3]));
  o.z = pk2(f2b(acc[4]), f2b(acc[5]));
  o.w = pk2(f2b(acc[6]), f2b(acc[7]));
  *(uint4*)(out + base + p0) = o;
}

// ---------------- inverse L2 norms of q and k over hw ----------------
__global__ __launch_bounds__(256) void k_rnorm(const u16* __restrict__ qkv, float* __restrict__ rqn,
                                               float* __restrict__ rkn, int b0) {
  int j = blockIdx.x, zb = blockIdx.y, b = b0 + zb, t = threadIdx.x;
  int ch = (j < 192) ? j : (384 + j - 192);
  const uint4* p = (const uint4*)(qkv + (((size_t)zb * C4_ + ch) << 14));
  float s = 0.f;
  for (int i = t; i < 2048; i += 256) {
    uint4 v = p[i];
    float a, c;
    b2f2(v.x, a, c); s += a * a + c * c;
    b2f2(v.y, a, c); s += a * a + c * c;
    b2f2(v.z, a, c); s += a * a + c * c;
    b2f2(v.w, a, c); s += a * a + c * c;
  }
  __shared__ float ss[256];
  ss[t] = s; __syncthreads();
  for (int o = 128; o > 0; o >>= 1) {
    if (t < o) ss[t] += ss[t + o];
    __syncthreads();
  }
  if (t == 0) {
    float r = 1.f / fmaxf(sqrtf(ss[0]), 1e-12f);
    if (j < 192) rqn[b * C_ + j] = r; else rkn[b * C_ + (j - 192)] = r;
  }
}

// ---------------- QK^T raw partial dots via MFMA ----------------
__global__ __launch_bounds__(256) void k_qk(const u16* __restrict__ qkv, float* __restrict__ Spart, int b0) {
  int split = blockIdx.x;
  int zb = blockIdx.y >> 2, h = blockIdx.y & 3;
  int bh = (b0 + zb) * 4 + h;
  int t = threadIdx.x, w = t >> 6, lane = t & 63, l16 = lane & 15, quad = lane >> 4;
  __shared__ alignas(16) u16 Qs[48][136];
  __shared__ alignas(16) u16 Ks[48][136];
  const u16* qb = qkv + (((size_t)zb * C4_ + h * 48) << 14);
  const u16* kb = qkv + (((size_t)zb * C4_ + 384 + h * 48) << 14);
  v4f acc[3][3] = {};
  for (int chunk = 0; chunk < 8; ++chunk) {
    int nb = split * 1024 + chunk * 128;
#pragma unroll
    for (int r = 0; r < 3; ++r) {
      int ci = r * 256 + t;         // 768 chunks of 8
      int row = ci >> 4, cs = (ci & 15) * 8;
      *(uint4*)&Qs[row][cs] = *(const uint4*)(qb + ((size_t)row << 14) + nb + cs);
      *(uint4*)&Ks[row][cs] = *(const uint4*)(kb + ((size_t)row << 14) + nb + cs);
    }
    __syncthreads();
    v8s qf[3], kf[3];
#pragma unroll
    for (int mt = 0; mt < 3; ++mt) qf[mt] = *(const v8s*)&Qs[mt * 16 + l16][w * 32 + quad * 8];
#pragma unroll
    for (int nt = 0; nt < 3; ++nt) kf[nt] = *(const v8s*)&Ks[nt * 16 + l16][w * 32 + quad * 8];
#pragma unroll
    for (int mt = 0; mt < 3; ++mt)
#pragma unroll
      for (int nt = 0; nt < 3; ++nt)
        acc[mt][nt] = __builtin_amdgcn_mfma_f32_16x16x32_bf16(qf[mt], kf[nt], acc[mt][nt], 0, 0, 0);
    __syncthreads();
  }
  float* out = Spart + ((size_t)(split * 4 + w) * 32 + bh) * 2304;
#pragma unroll
  for (int mt = 0; mt < 3; ++mt)
#pragma unroll
    for (int nt = 0; nt < 3; ++nt)
#pragma unroll
      for (int r = 0; r < 4; ++r)
        out[(mt * 16 + quad * 4 + r) * 48 + nt * 16 + l16] = acc[mt][nt][r];
}

// ---------------- fold norms+temperature, softmax rows ----------------
__global__ __launch_bounds__(256) void k_softmax(const float* __restrict__ Spart, const float* __restrict__ rqn,
                                                 const float* __restrict__ rkn, const float* __restrict__ temp,
                                                 float* __restrict__ attn, int b0) {
  int bh = b0 * 4 + blockIdx.x;
  int b = bh >> 2, h = bh & 3, t = threadIdx.x;
  __shared__ float Sm[2304];
  float tv = temp[h];
  for (int r = 0; r < 9; ++r) {
    int e = r * 256 + t;
    float s = 0.f;
    for (int p = 0; p < 64; ++p) s += Spart[((size_t)p * 32 + bh) * 2304 + e];
    int c = e / 48, d = e - c * 48;
    Sm[e] = s * rqn[b * C_ + h * 48 + c] * rkn[b * C_ + h * 48 + d] * tv;
  }
  __syncthreads();
  if (t < 48) {
    float m = -INFINITY;
#pragma unroll
    for (int d = 0; d < 48; ++d) m = fmaxf(m, Sm[t * 48 + d]);
    float ex[48];
    float sum = 0.f;
#pragma unroll
    for (int d = 0; d < 48; ++d) { ex[d] = expf(Sm[t * 48 + d] - m); sum += ex[d]; }
    float inv = 1.f / sum;
#pragma unroll
    for (int d = 0; d < 48; ++d) attn[(size_t)bh * 2304 + t * 48 + d] = ex[d] * inv;
  }
}

// ---------------- out = (attn @ v) * sigmoid(gate), stored as ogT[hw][c] bf16 ----------------
__global__ __launch_bounds__(256) void k_av(const u16* __restrict__ qkv, const float* __restrict__ attn,
                                            u16* __restrict__ ogT, int b0) {
  int zb = blockIdx.y >> 2, h = blockIdx.y & 3;
  int bh = (b0 + zb) * 4 + h;
  int t = threadIdx.x;
  int n0 = blockIdx.x * 512;
  __shared__ alignas(16) u16 Vs[48][520];
  __shared__ alignas(16) float SlT[48][48];   // [d][c]
  for (int r = 0; r < 9; ++r) {
    int e = r * 256 + t;
    int c = e / 48, d = e - c * 48;
    SlT[d][c] = attn[(size_t)bh * 2304 + e];
  }
  const u16* vb = qkv + (((size_t)zb * C4_ + 576 + h * 48) << 14);
  for (int r = 0; r < 12; ++r) {
    int ci = r * 256 + t;           // 48 rows * 64 chunks
    int row = ci >> 6, cs = (ci & 63) * 8;
    *(uint4*)&Vs[row][cs] = *(const uint4*)(vb + ((size_t)row << 14) + n0 + cs);
  }
  __syncthreads();
  int grp = t >> 6, nl = t & 63;
  int n = n0 + nl * 8;
  float acc[12][8] = {};
  for (int d = 0; d < 48; ++d) {
    uint4 vv = *(const uint4*)&Vs[d][nl * 8];
    float v[8];
    b2f2(vv.x, v[0], v[1]); b2f2(vv.y, v[2], v[3]);
    b2f2(vv.z, v[4], v[5]); b2f2(vv.w, v[6], v[7]);
    const float4* sr = (const float4*)&SlT[d][grp * 12];
    float4 sa = sr[0], sb = sr[1], sc = sr[2];
    float sv[12] = {sa.x, sa.y, sa.z, sa.w, sb.x, sb.y, sb.z, sb.w, sc.x, sc.y, sc.z, sc.w};
#pragma unroll
    for (int cc = 0; cc < 12; ++cc)
#pragma unroll
      for (int j = 0; j < 8; ++j) acc[cc][j] += sv[cc] * v[j];
  }
  const u16* gb = qkv + (((size_t)zb * C4_ + 192 + h * 48) << 14);
#pragma unroll
  for (int cc = 0; cc < 12; ++cc) {
    int c = grp * 12 + cc;
    uint4 g4 = *(const uint4*)(gb + ((size_t)c << 14) + n);
    float g[8];
    b2f2(g4.x, g[0], g[1]); b2f2(g4.y, g[2], g[3]);
    b2f2(g4.z, g[4], g[5]); b2f2(g4.w, g[6], g[7]);
#pragma unroll
    for (int j = 0; j < 8; ++j) acc[cc][j] *= sigm(g[j]);
  }
#pragma unroll
  for (int j = 0; j < 8; ++j) {
    u16 vals[12];
#pragma unroll
    for (int cc = 0; cc < 12; ++cc) vals[cc] = f2b(acc[cc][j]);
    u16* dst = ogT + ((size_t)zb * HW_ + n + j) * 192 + h * 48 + grp * 12;
    uint2* d2 = (uint2*)dst;        // 8-byte aligned
    uint2 w0, w1, w2;
    w0.x = pk2(vals[0], vals[1]);  w0.y = pk2(vals[2], vals[3]);
    w1.x = pk2(vals[4], vals[5]);  w1.y = pk2(vals[6], vals[7]);
    w2.x = pk2(vals[8], vals[9]);  w2.y = pk2(vals[10], vals[11]);
    d2[0] = w0; d2[1] = w1; d2[2] = w2;
  }
}

// ---------------- host ----------------
extern "C" void kernel_launch(void* const* d_in, const int* in_sizes, int n_in,
                              void* d_out, int out_size, void* d_ws, size_t ws_size,
                              hipStream_t stream) {
  const float* x     = (const float*)d_in[0];
  const float* wfc1  = (const float*)d_in[1];
  const float* wfc2  = (const float*)d_in[2];
  const float* wsp   = (const float*)d_in[3];
  const float* wqkv  = (const float*)d_in[4];
  const float* wdw   = (const float*)d_in[5];
  const float* wproj = (const float*)d_in[6];
  const float* temp  = (const float*)d_in[7];
  float* out = (float*)d_out;
  char* W = (char*)d_ws;

  constexpr size_t OFF_AVG   = 0;
  constexpr size_t OFF_MAX   = 8192;
  constexpr size_t OFF_CG    = 16384;
  constexpr size_t OFF_RQN   = 24576;
  constexpr size_t OFF_RKN   = 32768;
  constexpr size_t OFF_WQB   = 40960;
  constexpr size_t OFF_WPB   = OFF_WQB + 294912;
  constexpr size_t OFF_SP    = OFF_WPB + 73728;
  constexpr size_t OFF_SG    = OFF_SP + 1048576;
  constexpr size_t OFF_ATT   = OFF_SG + 524288;
  constexpr size_t OFF_SPART = OFF_ATT + 294912;
  constexpr size_t OFF_BIG   = OFF_SPART + 18874368;
  const size_t GXT_B = (size_t)HW_ * 192 * 2;        // 6291456
  const size_t QKV_B = (size_t)C4_ * HW_ * 2;        // 25165824

  float* avg   = (float*)(W + OFF_AVG);
  float* mx    = (float*)(W + OFF_MAX);
  float* cg    = (float*)(W + OFF_CG);
  float* rqn   = (float*)(W + OFF_RQN);
  float* rkn   = (float*)(W + OFF_RKN);
  u16*   wqb   = (u16*)(W + OFF_WQB);
  u16*   wpb   = (u16*)(W + OFF_WPB);
  float* sp    = (float*)(W + OFF_SP);
  float* sg    = (float*)(W + OFF_SG);
  float* attn  = (float*)(W + OFF_ATT);
  float* Spart = (float*)(W + OFF_SPART);

  int NB = 8;
  while (NB > 1 && (OFF_BIG + (size_t)NB * (GXT_B + 2 * QKV_B)) > ws_size) NB >>= 1;

  u16* gxT  = (u16*)(W + OFF_BIG);
  u16* qkvr = (u16*)(W + OFF_BIG + (size_t)NB * GXT_B);
  u16* qkvd = (u16*)(W + OFF_BIG + (size_t)NB * (GXT_B + QKV_B));
  u16* ogT  = qkvr;   // qkv_raw dead once depthwise is done for the whole group

  k_f2b<<<(147456 + 255) / 256, 256, 0, stream>>>(wqkv, wqb, 147456);
  k_f2b<<<(36864 + 255) / 256, 256, 0, stream>>>(wproj, wpb, 36864);
  k_channel_pool<<<dim3(C_, B_), 256, 0, stream>>>(x, avg, mx);
  k_channel_gate<<<B_, 256, 0, stream>>>(avg, mx, wfc1, wfc2, cg);
  k_spatial_pool<<<dim3(64, B_), 256, 0, stream>>>(x, sp);
  k_spatial_conv<<<dim3(64, B_), 256, 0, stream>>>(sp, wsp, sg);

  for (int b0 = 0; b0 < B_; b0 += NB) {
    k_gxT<<<dim3(256, NB), 256, 0, stream>>>(x, cg, sg, gxT, b0);
    gemm_bt<768, u16><<<dim3(128, 6, NB), 256, 0, stream>>>(wqb, gxT, qkvr);
    k_dw<<<dim3(8, C4_, NB), 256, 0, stream>>>(qkvr, wdw, qkvd);
    k_rnorm<<<dim3(384, NB), 256, 0, stream>>>(qkvd, rqn, rkn, b0);
    k_qk<<<dim3(16, NB * 4), 256, 0, stream>>>(qkvd, Spart, b0);
    k_softmax<<<NB * 4, 256, 0, stream>>>(Spart, rqn, rkn, temp, attn, b0);
    k_av<<<dim3(32, NB * 4), 256, 0, stream>>>(qkvd, attn, ogT, b0);
    gemm_bt<192, float><<<dim3(128, 2, NB), 256, 0, stream>>>(wpb, ogT, out + (size_t)b0 * C_ * HW_);
  }
}